// Round 11
// baseline (1202.710 us; speedup 1.0000x reference)
//
#include <hip/hip_runtime.h>

// TAGConv L3: N=100000, E=3200000, K=3. dims (16->128)(128->128)(128->128)(128->4).
// R10: GEMM B-operand read DIRECT from global (L2-resident weights; no Bs LDS stage);
//      scan2 folded into scan3 (per-block prefix over bsum); xcast folded into wprep.
//      Else = R9: packed 4B CSR, compact hop buffers, one-node-per-wave props,
//      Z-fused layer-2 GEMM, packed-u64 atomic CSR build, d=4 Horner layer 3.

typedef __attribute__((ext_vector_type(8))) short bf16x8v;   // 8 bf16 = 4 VGPR
typedef __attribute__((ext_vector_type(4))) float f32x4v;

__device__ __forceinline__ float bflo(unsigned int u) { return __uint_as_float(u << 16); }
__device__ __forceinline__ float bfhi(unsigned int u) { return __uint_as_float(u & 0xffff0000u); }
__device__ __forceinline__ unsigned short f2bf(float f) {
    unsigned int u = __float_as_uint(f);
    u = (u + 0x7fff + ((u >> 16) & 1)) >> 16;   // RNE
    return (unsigned short)u;
}
__device__ __forceinline__ unsigned int pack2bf(float lo, float hi) {
    return (unsigned int)f2bf(lo) | ((unsigned int)f2bf(hi) << 16);
}
// packed CSR decode
__device__ __forceinline__ unsigned int csr_src(unsigned int v) { return v >> 15; }
__device__ __forceinline__ float csr_w(unsigned int v) { return __uint_as_float((v & 0x7FFFu) << 16); }

// ---------------- pass 1: packed deg/count atomic + per-edge rank ----------------
__global__ void k_edge_deg(const int* __restrict__ dst, const float* __restrict__ ew,
                           unsigned long long* __restrict__ dc,
                           unsigned short* __restrict__ rank, int E) {
    int stride = gridDim.x * blockDim.x;
    for (int e = blockIdx.x * blockDim.x + threadIdx.x; e < E; e += stride) {
        int d = dst[e];
        unsigned long long fx = (unsigned long long)(ew[e] * 0x1p40f);
        unsigned long long old = atomicAdd(&dc[d], (fx << 12) | 1ULL);
        rank[e] = (unsigned short)(old & 0xFFFULL);
    }
}

// ---------------- scan phase 1 (+ dis fused) ----------------
__global__ void k_scan1(const unsigned long long* __restrict__ dc, int* __restrict__ bsum,
                        float* __restrict__ dis, int N) {
    __shared__ int s[256];
    int tid = threadIdx.x;
    int base = blockIdx.x * 1024 + tid * 4;
    int t = 0;
    #pragma unroll
    for (int i = 0; i < 4; ++i) {
        int idx = base + i;
        if (idx < N) {
            unsigned long long v = dc[idx];
            t += (int)(v & 0xFFFULL);
            float d = (float)(v >> 12) * 0x1p-40f;
            dis[idx] = d > 0.f ? rsqrtf(d) : 0.f;
        }
    }
    s[tid] = t; __syncthreads();
    for (int off = 128; off > 0; off >>= 1) {
        if (tid < off) s[tid] += s[tid + off];
        __syncthreads();
    }
    if (tid == 0) bsum[blockIdx.x] = s[0];
}

// ---------------- scan phase 2: row_ptr, with in-block prefix over bsum ----------------
__global__ void k_scan3(const unsigned long long* __restrict__ dc, const int* __restrict__ bsum,
                        int* __restrict__ row_ptr, int N, int nsb) {
    __shared__ int s[256];
    __shared__ int blockoff;
    int tid = threadIdx.x;
    // prefix of bsum[0..blockIdx) (nsb <= 256)
    s[tid] = (tid < blockIdx.x && tid < nsb) ? bsum[tid] : 0;
    __syncthreads();
    for (int off = 128; off > 0; off >>= 1) {
        if (tid < off) s[tid] += s[tid + off];
        __syncthreads();
    }
    if (tid == 0) blockoff = s[0];
    __syncthreads();

    int base = blockIdx.x * 1024 + tid * 4;
    int v[4]; int t = 0;
    #pragma unroll
    for (int i = 0; i < 4; ++i) { int idx = base + i; v[i] = (idx < N) ? (int)(dc[idx] & 0xFFFULL) : 0; t += v[i]; }
    s[tid] = t; __syncthreads();
    for (int off = 1; off < 256; off <<= 1) {
        int add = (tid >= off) ? s[tid - off] : 0;
        __syncthreads();
        s[tid] += add;
        __syncthreads();
    }
    int g = blockoff + (s[tid] - t);   // exclusive prefix
    #pragma unroll
    for (int i = 0; i < 4; ++i) {
        int idx = base + i;
        if (idx < N) row_ptr[idx] = g;
        g += v[i];
    }
    if (blockIdx.x == nsb - 1 && tid == 255) row_ptr[N] = blockoff + s[255];
}

// ---------------- pass 2: atomic-free CSR fill (packed 4B entries) ----------------
__global__ void k_fill_csr(const int* __restrict__ src, const int* __restrict__ dst,
                           const float* __restrict__ ew, const float* __restrict__ dis,
                           const int* __restrict__ row_ptr, const unsigned short* __restrict__ rank,
                           unsigned int* __restrict__ csr, int E) {
    int stride = gridDim.x * blockDim.x;
    for (int e = blockIdx.x * blockDim.x + threadIdx.x; e < E; e += stride) {
        int d = dst[e];
        unsigned int s = (unsigned int)src[e];
        int pos = row_ptr[d] + rank[e];
        float w = dis[s] * ew[e] * dis[d];
        csr[pos] = (s << 15) | ((unsigned int)f2bf(w) & 0x7FFFu);
    }
}

// ---------------- weight prep + x cast (one kernel) ----------------
__global__ void k_wprep_all(const float* __restrict__ W0, const float* __restrict__ W1,
                            const float* __restrict__ W2, const float* __restrict__ W3,
                            const float* __restrict__ x,
                            unsigned short* __restrict__ Wt0, unsigned short* __restrict__ Wt1,
                            unsigned short* __restrict__ Wt2, unsigned short* __restrict__ Wz,
                            unsigned short* __restrict__ H0, int nx8) {
    int t = blockIdx.x * blockDim.x + threadIdx.x;
    if (t < 8192) {
        int c = t >> 6, r = t & 63;
        Wt0[t] = f2bf(W0[r * 128 + c]);
    } else if (t < 8192 + 65536) {
        int u = t - 8192; int c = u >> 9, r = u & 511;
        Wt1[u] = f2bf(W1[r * 128 + c]);
    } else if (t < 8192 + 131072) {
        int u = t - (8192 + 65536); int c = u >> 9, r = u & 511;
        Wt2[u] = f2bf(W2[r * 128 + c]);
    } else if (t < 8192 + 131072 + 2048) {
        int u = t - (8192 + 131072); int c = u >> 7, k = u & 127;
        Wz[u] = f2bf(W3[(c >> 2) * 512 + k * 4 + (c & 3)]);
    } else if (t < 8192 + 131072 + 2048 + nx8) {
        int u = t - (8192 + 131072 + 2048);
        float4 v0 = *reinterpret_cast<const float4*>(&x[u * 8]);
        float4 v1 = *reinterpret_cast<const float4*>(&x[u * 8 + 4]);
        uint4 o;
        o.x = pack2bf(v0.x, v0.y); o.y = pack2bf(v0.z, v0.w);
        o.z = pack2bf(v1.x, v1.y); o.w = pack2bf(v1.z, v1.w);
        *reinterpret_cast<uint4*>(&H0[u * 8]) = o;
    }
}

// ---------------- prop d=16: one node/wave, 16 edges x 4 lanes, compact stride 16 ----------------
__global__ __launch_bounds__(256) void k_prop16b(const unsigned short* __restrict__ hin,
                                                 unsigned short* __restrict__ bout,
                                                 const int* __restrict__ row_ptr,
                                                 const unsigned int* __restrict__ csr, int N) {
    int node = blockIdx.x * 4 + (threadIdx.x >> 6);
    if (node >= N) return;
    int lane = threadIdx.x & 63;
    int esub = lane >> 2, f4 = (lane & 3) * 4;
    int s = row_ptr[node], e = row_ptr[node + 1];
    float a0 = 0.f, a1 = 0.f, a2 = 0.f, a3 = 0.f;
    for (int i = s + esub; i < e; i += 16) {
        unsigned int ed = csr[i];
        float w = csr_w(ed);
        uint2 r = *reinterpret_cast<const uint2*>(&hin[(size_t)csr_src(ed) * 16 + f4]);
        a0 += w * bflo(r.x); a1 += w * bfhi(r.x);
        a2 += w * bflo(r.y); a3 += w * bfhi(r.y);
    }
    #pragma unroll
    for (int m = 4; m <= 32; m <<= 1) {
        a0 += __shfl_xor(a0, m); a1 += __shfl_xor(a1, m);
        a2 += __shfl_xor(a2, m); a3 += __shfl_xor(a3, m);
    }
    if (lane < 4) {
        uint2 ob; ob.x = pack2bf(a0, a1); ob.y = pack2bf(a2, a3);
        *reinterpret_cast<uint2*>(&bout[(size_t)node * 16 + f4]) = ob;
    }
}

// ---------------- prop d=128: one node/wave, 16 edges in flight (4/lane) ----------------
__global__ __launch_bounds__(256) void k_prop128b(const unsigned short* __restrict__ hin, int gs,
                                                  unsigned short* __restrict__ bout, int os,
                                                  const int* __restrict__ row_ptr,
                                                  const unsigned int* __restrict__ csr, int N) {
    int node = blockIdx.x * 4 + (threadIdx.x >> 6);
    if (node >= N) return;
    int lane = threadIdx.x & 63;
    int esub = lane >> 4, f8 = (lane & 15) * 8;
    int s = row_ptr[node], e = row_ptr[node + 1];
    float a0 = 0.f, a1 = 0.f, a2 = 0.f, a3 = 0.f;
    float a4 = 0.f, a5 = 0.f, a6 = 0.f, a7 = 0.f;
    int i = s;
    for (; i + 16 <= e; i += 16) {
        unsigned int e0 = csr[i + esub],     e1 = csr[i + esub + 4];
        unsigned int e2 = csr[i + esub + 8], e3 = csr[i + esub + 12];
        uint4 r0 = *reinterpret_cast<const uint4*>(&hin[(size_t)csr_src(e0) * gs + f8]);
        uint4 r1 = *reinterpret_cast<const uint4*>(&hin[(size_t)csr_src(e1) * gs + f8]);
        uint4 r2 = *reinterpret_cast<const uint4*>(&hin[(size_t)csr_src(e2) * gs + f8]);
        uint4 r3 = *reinterpret_cast<const uint4*>(&hin[(size_t)csr_src(e3) * gs + f8]);
        float w0 = csr_w(e0), w1 = csr_w(e1), w2 = csr_w(e2), w3 = csr_w(e3);
        a0 += w0 * bflo(r0.x) + w1 * bflo(r1.x) + w2 * bflo(r2.x) + w3 * bflo(r3.x);
        a1 += w0 * bfhi(r0.x) + w1 * bfhi(r1.x) + w2 * bfhi(r2.x) + w3 * bfhi(r3.x);
        a2 += w0 * bflo(r0.y) + w1 * bflo(r1.y) + w2 * bflo(r2.y) + w3 * bflo(r3.y);
        a3 += w0 * bfhi(r0.y) + w1 * bfhi(r1.y) + w2 * bfhi(r2.y) + w3 * bfhi(r3.y);
        a4 += w0 * bflo(r0.z) + w1 * bflo(r1.z) + w2 * bflo(r2.z) + w3 * bflo(r3.z);
        a5 += w0 * bfhi(r0.z) + w1 * bfhi(r1.z) + w2 * bfhi(r2.z) + w3 * bfhi(r3.z);
        a6 += w0 * bflo(r0.w) + w1 * bflo(r1.w) + w2 * bflo(r2.w) + w3 * bflo(r3.w);
        a7 += w0 * bfhi(r0.w) + w1 * bfhi(r1.w) + w2 * bfhi(r2.w) + w3 * bfhi(r3.w);
    }
    for (int ii = i + esub; ii < e; ii += 4) {
        unsigned int ed = csr[ii];
        float w = csr_w(ed);
        uint4 r = *reinterpret_cast<const uint4*>(&hin[(size_t)csr_src(ed) * gs + f8]);
        a0 += w * bflo(r.x); a1 += w * bfhi(r.x);
        a2 += w * bflo(r.y); a3 += w * bfhi(r.y);
        a4 += w * bflo(r.z); a5 += w * bfhi(r.z);
        a6 += w * bflo(r.w); a7 += w * bfhi(r.w);
    }
    #pragma unroll
    for (int m = 16; m <= 32; m <<= 1) {
        a0 += __shfl_xor(a0, m); a1 += __shfl_xor(a1, m);
        a2 += __shfl_xor(a2, m); a3 += __shfl_xor(a3, m);
        a4 += __shfl_xor(a4, m); a5 += __shfl_xor(a5, m);
        a6 += __shfl_xor(a6, m); a7 += __shfl_xor(a7, m);
    }
    if (lane < 16) {
        uint4 ob;
        ob.x = pack2bf(a0, a1); ob.y = pack2bf(a2, a3);
        ob.z = pack2bf(a4, a5); ob.w = pack2bf(a6, a7);
        *reinterpret_cast<uint4*>(&bout[(size_t)node * os + f8]) = ob;
    }
}

// ---------------- prop d=4 with add: 16 lanes/node, 4 edges parallel ----------------
__global__ __launch_bounds__(256) void k_prop4_add(const float* __restrict__ tin,
                                                   const float* __restrict__ zadd,
                                                   const float* __restrict__ bias,
                                                   float* __restrict__ tout,
                                                   const int* __restrict__ row_ptr,
                                                   const unsigned int* __restrict__ csr, int N) {
    int node = blockIdx.x * 16 + (threadIdx.x >> 4);
    if (node >= N) return;
    int lane = threadIdx.x & 15;
    int esub = lane >> 2, j = lane & 3;
    int s = row_ptr[node], e = row_ptr[node + 1];
    float a = 0.f;
    for (int i = s + esub; i < e; i += 4) {
        unsigned int ed = csr[i];
        a += csr_w(ed) * tin[(size_t)csr_src(ed) * 4 + j];
    }
    a += __shfl_xor(a, 4);
    a += __shfl_xor(a, 8);
    if (esub == 0) {
        float v = a + zadd[(size_t)node * 4 + j];
        if (bias) v += bias[j];
        tout[(size_t)node * 4 + j] = v;
    }
}

// ---------------- MFMA GEMM: C(Mx128)bf16 = relu(A(MxK)bf16 @ Bt(128xK)^T + bias) ----------------
// A staged in LDS; B read DIRECT from global (L2-resident, 16B-aligned fragment loads).
// A from 4 hop buffers: !L0 -> hop = kt>>7; L0 -> hop = off>>4 (K=64, 16 cols each).
// FUSEZ: Z planes (4 x N x 4 fp32) = relu'd-h @ Wz^T via LDS round-trip; Cout write skipped.
template <bool L0, bool FUSEZ>
__global__ __launch_bounds__(256) void k_mfma_gemm(const unsigned short* __restrict__ a0p, int s0,
                                                   const unsigned short* __restrict__ a1p, int s1,
                                                   const unsigned short* __restrict__ a2p, int s2,
                                                   const unsigned short* __restrict__ a3p, int s3,
                                                   int K,
                                                   const unsigned short* __restrict__ Bt,
                                                   const float* __restrict__ bias,
                                                   unsigned short* __restrict__ Coutb,
                                                   const unsigned short* __restrict__ Wzg,
                                                   float* __restrict__ Zout, int M) {
    __shared__ unsigned short smem[19584];   // As[128][72]; reused as Hs[128][136] + WzS[16][136]
    unsigned short (*As)[72] = reinterpret_cast<unsigned short(*)[72]>(smem);
    const unsigned short* Ab[4] = { a0p, a1p, a2p, a3p };
    int Ast[4] = { s0, s1, s2, s3 };
    int tid = threadIdx.x;
    int r0 = blockIdx.x * 128;
    int wid = tid >> 6, lane = tid & 63;
    int wm = (wid >> 1) * 64, wn = (wid & 1) * 64;
    f32x4v acc[4][4];
    #pragma unroll
    for (int a = 0; a < 4; ++a)
        #pragma unroll
        for (int b = 0; b < 4; ++b) acc[a][b] = (f32x4v){0.f, 0.f, 0.f, 0.f};

    int rsel = lane & 15, ksel = (lane >> 4) * 8;

    for (int kt = 0; kt < K; kt += 64) {
        #pragma unroll
        for (int i = 0; i < 4; ++i) {
            int c = tid + i * 256;             // 1024 x 16B chunks: A tile 128 x 64 bf16
            int row = c >> 3, off = (c & 7) * 8;
            int gr = r0 + row;
            int4 v = make_int4(0, 0, 0, 0);
            if (L0) {
                int hop = off >> 4, col0 = off & 15;
                if (gr < M) v = *reinterpret_cast<const int4*>(Ab[hop] + (size_t)gr * 16 + col0);
            } else {
                int hop = kt >> 7, kb = kt & 127;
                if (gr < M) v = *reinterpret_cast<const int4*>(Ab[hop] + (size_t)gr * Ast[hop] + kb + off);
            }
            *reinterpret_cast<int4*>(&As[row][off]) = v;
        }
        __syncthreads();
        #pragma unroll
        for (int kc = 0; kc < 64; kc += 32) {
            bf16x8v af[4], bfv[4];
            #pragma unroll
            for (int f = 0; f < 4; ++f) {
                af[f]  = *reinterpret_cast<const bf16x8v*>(&As[wm + f * 16 + rsel][kc + ksel]);
                bfv[f] = *reinterpret_cast<const bf16x8v*>(Bt + (size_t)(wn + f * 16 + rsel) * K + kt + kc + ksel);
            }
            #pragma unroll
            for (int mf = 0; mf < 4; ++mf)
                #pragma unroll
                for (int nf = 0; nf < 4; ++nf)
                    acc[mf][nf] = __builtin_amdgcn_mfma_f32_16x16x32_bf16(af[mf], bfv[nf], acc[mf][nf], 0, 0, 0);
        }
        __syncthreads();
    }
    // epilogue: C/D layout col=lane&15, row=(lane>>4)*4+reg
    int col_l = lane & 15, rgrp = (lane >> 4) * 4;
    unsigned short* Hs = smem;              // [128][136]
    unsigned short* WzS = smem + 17408;     // [16][136]
    #pragma unroll
    for (int nf = 0; nf < 4; ++nf) {
        int col = wn + nf * 16 + col_l;
        float bv = bias[col];
        #pragma unroll
        for (int mf = 0; mf < 4; ++mf) {
            #pragma unroll
            for (int j = 0; j < 4; ++j) {
                int lrow = wm + mf * 16 + rgrp + j;
                float v = fmaxf(acc[mf][nf][j] + bv, 0.f);
                unsigned short hb = f2bf(v);
                if (FUSEZ) {
                    Hs[lrow * 136 + col] = hb;
                } else {
                    int row = r0 + lrow;
                    if (row < M) Coutb[(size_t)row * 128 + col] = hb;
                }
            }
        }
    }
    if (FUSEZ) {
        for (int t = tid; t < 2048; t += 256) {
            WzS[(t >> 7) * 136 + (t & 127)] = Wzg[t];
        }
        __syncthreads();
        int wmz = wid * 32;
        f32x4v z0 = (f32x4v){0.f, 0.f, 0.f, 0.f};
        f32x4v z1 = (f32x4v){0.f, 0.f, 0.f, 0.f};
        #pragma unroll
        for (int kt2 = 0; kt2 < 128; kt2 += 32) {
            bf16x8v aa0 = *reinterpret_cast<const bf16x8v*>(&Hs[(wmz + rsel) * 136 + kt2 + ksel]);
            bf16x8v aa1 = *reinterpret_cast<const bf16x8v*>(&Hs[(wmz + 16 + rsel) * 136 + kt2 + ksel]);
            bf16x8v bz = *reinterpret_cast<const bf16x8v*>(&WzS[rsel * 136 + kt2 + ksel]);
            z0 = __builtin_amdgcn_mfma_f32_16x16x32_bf16(aa0, bz, z0, 0, 0, 0);
            z1 = __builtin_amdgcn_mfma_f32_16x16x32_bf16(aa1, bz, z1, 0, 0, 0);
        }
        // Z planes: plane = col>>2, within-plane col = col&3
        size_t plane = (size_t)(col_l >> 2) * (size_t)M * 4;
        int cj = col_l & 3;
        #pragma unroll
        for (int j = 0; j < 4; ++j) {
            int ra = r0 + wmz + rgrp + j;
            if (ra < M) Zout[plane + (size_t)ra * 4 + cj] = z0[j];
            int rb = r0 + wmz + 16 + rgrp + j;
            if (rb < M) Zout[plane + (size_t)rb * 4 + cj] = z1[j];
        }
    }
}

// ---------------- launch ----------------
extern "C" void kernel_launch(void* const* d_in, const int* in_sizes, int n_in,
                              void* d_out, int out_size, void* d_ws, size_t ws_size,
                              hipStream_t stream) {
    const float* x  = (const float*)d_in[0];
    const int*   ei = (const int*)d_in[1];
    const float* ew = (const float*)d_in[2];
    const float* W0 = (const float*)d_in[3];
    const float* b0 = (const float*)d_in[4];
    const float* W1 = (const float*)d_in[5];
    const float* b1 = (const float*)d_in[6];
    const float* W2 = (const float*)d_in[7];
    const float* b2 = (const float*)d_in[8];
    const float* W3 = (const float*)d_in[9];
    const float* b3 = (const float*)d_in[10];
    float* out = (float*)d_out;

    const int N = in_sizes[0] / 16;   // 100000
    const int E = in_sizes[2];        // 3200000
    const int* src = ei;
    const int* dst = ei + E;

    char* ws = (char*)d_ws;
    size_t off = 0;
    auto take = [&](size_t bytes) -> void* {
        void* p = ws + off;
        off = (off + bytes + 255) & ~(size_t)255;
        return p;
    };
    unsigned short* S   = (unsigned short*)take((size_t)N * 384 * 2);  // hop slots 1..3 (stride 384)
    unsigned short* Qa  = (unsigned short*)take((size_t)N * 128 * 2);
    unsigned short* Qb  = (unsigned short*)take((size_t)N * 128 * 2);
    unsigned short* H0  = (unsigned short*)take((size_t)N * 16 * 2);  // layer-0 compact hops
    unsigned short* H1  = (unsigned short*)take((size_t)N * 16 * 2);
    unsigned short* H2  = (unsigned short*)take((size_t)N * 16 * 2);
    unsigned short* H3  = (unsigned short*)take((size_t)N * 16 * 2);
    unsigned int*  csr  = (unsigned int*) take((size_t)E * 4);        // packed (src<<15)|bf16w15
    unsigned long long* dc = (unsigned long long*)take((size_t)N * 8);
    unsigned short* rank = (unsigned short*)take((size_t)E * 2);
    float* dis     = (float*)take((size_t)N * 4);
    int*   row_ptr = (int*)  take((size_t)(N + 1) * 4);
    int*   bsum    = (int*)  take(1024);
    float* Z       = (float*)take((size_t)N * 16 * 4);   // 4 planes of N x 4
    float* T1      = (float*)take((size_t)N * 4 * 4);
    float* T2      = (float*)take((size_t)N * 4 * 4);
    unsigned short* Wt0 = (unsigned short*)take(64 * 128 * 2);
    unsigned short* Wt1 = (unsigned short*)take(512 * 128 * 2);
    unsigned short* Wt2 = (unsigned short*)take(512 * 128 * 2);
    unsigned short* Wz  = (unsigned short*)take(16 * 128 * 2);

    // ---- build norm + CSR (one packed atomic pass, atomic-free fill) ----
    hipMemsetAsync(dc, 0, (size_t)N * 8, stream);
    k_edge_deg<<<2048, 256, 0, stream>>>(dst, ew, dc, rank, E);
    int nsb = (N + 1023) / 1024;
    k_scan1<<<nsb, 256, 0, stream>>>(dc, bsum, dis, N);
    k_scan3<<<nsb, 256, 0, stream>>>(dc, bsum, row_ptr, N, nsb);
    k_fill_csr<<<2048, 256, 0, stream>>>(src, dst, ew, dis, row_ptr, rank, csr, E);

    // ---- weight prep + x cast (one kernel) ----
    int nx8 = N * 2;
    k_wprep_all<<<(141312 + nx8 + 255) / 256, 256, 0, stream>>>(W0, W1, W2, W3, x,
                                                                Wt0, Wt1, Wt2, Wz, H0, nx8);

    int gmfma = (N + 127) / 128;
    int gpw   = (N + 3) / 4;      // one node per wave, 4 waves/block
    size_t N4 = (size_t)N * 4;

    // ---- layer 0: 16 -> 128 (compact bf16 hop chain H0..H3) ----
    k_prop16b<<<gpw, 256, 0, stream>>>(H0, H1, row_ptr, csr, N);
    k_prop16b<<<gpw, 256, 0, stream>>>(H1, H2, row_ptr, csr, N);
    k_prop16b<<<gpw, 256, 0, stream>>>(H2, H3, row_ptr, csr, N);
    k_mfma_gemm<true, false><<<gmfma, 256, 0, stream>>>(H0, 16, H1, 16, H2, 16, H3, 16,
                                                        64, Wt0, b0, Qa, nullptr, nullptr, N);

    // ---- layer 1: 128 -> 128 ----
    k_prop128b<<<gpw, 256, 0, stream>>>(Qa, 128,      S + 0,   384, row_ptr, csr, N);
    k_prop128b<<<gpw, 256, 0, stream>>>(S + 0, 384,   S + 128, 384, row_ptr, csr, N);
    k_prop128b<<<gpw, 256, 0, stream>>>(S + 128, 384, S + 256, 384, row_ptr, csr, N);
    k_mfma_gemm<false, false><<<gmfma, 256, 0, stream>>>(Qa, 128, S + 0, 384, S + 128, 384, S + 256, 384,
                                                         512, Wt1, b1, Qb, nullptr, nullptr, N);

    // ---- layer 2: 128 -> 128, Z fused into epilogue ----
    k_prop128b<<<gpw, 256, 0, stream>>>(Qb, 128,      S + 0,   384, row_ptr, csr, N);
    k_prop128b<<<gpw, 256, 0, stream>>>(S + 0, 384,   S + 128, 384, row_ptr, csr, N);
    k_prop128b<<<gpw, 256, 0, stream>>>(S + 128, 384, S + 256, 384, row_ptr, csr, N);
    k_mfma_gemm<false, true><<<gmfma, 256, 0, stream>>>(Qb, 128, S + 0, 384, S + 128, 384, S + 256, 384,
                                                        512, Wt2, b2, nullptr, Wz, Z, N);

    // ---- layer 3: 128 -> 4 via projected Horner on Z planes ----
    {
        int g = (N + 15) / 16;
        k_prop4_add<<<g, 256, 0, stream>>>(Z + 3 * N4, Z + 2 * N4, nullptr, T1, row_ptr, csr, N);
        k_prop4_add<<<g, 256, 0, stream>>>(T1,         Z + 1 * N4, nullptr, T2, row_ptr, csr, N);
        k_prop4_add<<<g, 256, 0, stream>>>(T2,         Z + 0 * N4, b3,      out, row_ptr, csr, N);
    }
}

// Round 12
// 1152.212 us; speedup vs baseline: 1.0438x; 1.0438x over previous
//
#include <hip/hip_runtime.h>

// TAGConv L3: N=100000, E=3200000, K=3. dims (16->128)(128->128)(128->128)(128->4).
// R11: REVERT R10's B-direct-from-global GEMM (regressed +40us: per-wave VMEM fragment
//      loads on MFMA critical path, no cross-wave sharing) -> back to R9's As+Bs LDS
//      staging. KEEP R10's dispatch trims: scan2 folded into scan3, xcast in wprep_all.
//      Else = R9: packed 4B CSR, compact hop buffers, one-node-per-wave props,
//      Z-fused layer-2 GEMM, packed-u64 atomic CSR build, d=4 Horner layer 3.

typedef __attribute__((ext_vector_type(8))) short bf16x8v;   // 8 bf16 = 4 VGPR
typedef __attribute__((ext_vector_type(4))) float f32x4v;

__device__ __forceinline__ float bflo(unsigned int u) { return __uint_as_float(u << 16); }
__device__ __forceinline__ float bfhi(unsigned int u) { return __uint_as_float(u & 0xffff0000u); }
__device__ __forceinline__ unsigned short f2bf(float f) {
    unsigned int u = __float_as_uint(f);
    u = (u + 0x7fff + ((u >> 16) & 1)) >> 16;   // RNE
    return (unsigned short)u;
}
__device__ __forceinline__ unsigned int pack2bf(float lo, float hi) {
    return (unsigned int)f2bf(lo) | ((unsigned int)f2bf(hi) << 16);
}
// packed CSR decode
__device__ __forceinline__ unsigned int csr_src(unsigned int v) { return v >> 15; }
__device__ __forceinline__ float csr_w(unsigned int v) { return __uint_as_float((v & 0x7FFFu) << 16); }

// ---------------- pass 1: packed deg/count atomic + per-edge rank ----------------
__global__ void k_edge_deg(const int* __restrict__ dst, const float* __restrict__ ew,
                           unsigned long long* __restrict__ dc,
                           unsigned short* __restrict__ rank, int E) {
    int stride = gridDim.x * blockDim.x;
    for (int e = blockIdx.x * blockDim.x + threadIdx.x; e < E; e += stride) {
        int d = dst[e];
        unsigned long long fx = (unsigned long long)(ew[e] * 0x1p40f);
        unsigned long long old = atomicAdd(&dc[d], (fx << 12) | 1ULL);
        rank[e] = (unsigned short)(old & 0xFFFULL);
    }
}

// ---------------- scan phase 1 (+ dis fused) ----------------
__global__ void k_scan1(const unsigned long long* __restrict__ dc, int* __restrict__ bsum,
                        float* __restrict__ dis, int N) {
    __shared__ int s[256];
    int tid = threadIdx.x;
    int base = blockIdx.x * 1024 + tid * 4;
    int t = 0;
    #pragma unroll
    for (int i = 0; i < 4; ++i) {
        int idx = base + i;
        if (idx < N) {
            unsigned long long v = dc[idx];
            t += (int)(v & 0xFFFULL);
            float d = (float)(v >> 12) * 0x1p-40f;
            dis[idx] = d > 0.f ? rsqrtf(d) : 0.f;
        }
    }
    s[tid] = t; __syncthreads();
    for (int off = 128; off > 0; off >>= 1) {
        if (tid < off) s[tid] += s[tid + off];
        __syncthreads();
    }
    if (tid == 0) bsum[blockIdx.x] = s[0];
}

// ---------------- scan phase 2: row_ptr, with in-block prefix over bsum ----------------
__global__ void k_scan3(const unsigned long long* __restrict__ dc, const int* __restrict__ bsum,
                        int* __restrict__ row_ptr, int N, int nsb) {
    __shared__ int s[256];
    __shared__ int blockoff;
    int tid = threadIdx.x;
    s[tid] = (tid < blockIdx.x && tid < nsb) ? bsum[tid] : 0;
    __syncthreads();
    for (int off = 128; off > 0; off >>= 1) {
        if (tid < off) s[tid] += s[tid + off];
        __syncthreads();
    }
    if (tid == 0) blockoff = s[0];
    __syncthreads();

    int base = blockIdx.x * 1024 + tid * 4;
    int v[4]; int t = 0;
    #pragma unroll
    for (int i = 0; i < 4; ++i) { int idx = base + i; v[i] = (idx < N) ? (int)(dc[idx] & 0xFFFULL) : 0; t += v[i]; }
    s[tid] = t; __syncthreads();
    for (int off = 1; off < 256; off <<= 1) {
        int add = (tid >= off) ? s[tid - off] : 0;
        __syncthreads();
        s[tid] += add;
        __syncthreads();
    }
    int g = blockoff + (s[tid] - t);   // exclusive prefix
    #pragma unroll
    for (int i = 0; i < 4; ++i) {
        int idx = base + i;
        if (idx < N) row_ptr[idx] = g;
        g += v[i];
    }
    if (blockIdx.x == nsb - 1 && tid == 255) row_ptr[N] = blockoff + s[255];
}

// ---------------- pass 2: atomic-free CSR fill (packed 4B entries) ----------------
__global__ void k_fill_csr(const int* __restrict__ src, const int* __restrict__ dst,
                           const float* __restrict__ ew, const float* __restrict__ dis,
                           const int* __restrict__ row_ptr, const unsigned short* __restrict__ rank,
                           unsigned int* __restrict__ csr, int E) {
    int stride = gridDim.x * blockDim.x;
    for (int e = blockIdx.x * blockDim.x + threadIdx.x; e < E; e += stride) {
        int d = dst[e];
        unsigned int s = (unsigned int)src[e];
        int pos = row_ptr[d] + rank[e];
        float w = dis[s] * ew[e] * dis[d];
        csr[pos] = (s << 15) | ((unsigned int)f2bf(w) & 0x7FFFu);
    }
}

// ---------------- weight prep + x cast (one kernel) ----------------
__global__ void k_wprep_all(const float* __restrict__ W0, const float* __restrict__ W1,
                            const float* __restrict__ W2, const float* __restrict__ W3,
                            const float* __restrict__ x,
                            unsigned short* __restrict__ Wt0, unsigned short* __restrict__ Wt1,
                            unsigned short* __restrict__ Wt2, unsigned short* __restrict__ Wz,
                            unsigned short* __restrict__ H0, int nx8) {
    int t = blockIdx.x * blockDim.x + threadIdx.x;
    if (t < 8192) {
        int c = t >> 6, r = t & 63;
        Wt0[t] = f2bf(W0[r * 128 + c]);
    } else if (t < 8192 + 65536) {
        int u = t - 8192; int c = u >> 9, r = u & 511;
        Wt1[u] = f2bf(W1[r * 128 + c]);
    } else if (t < 8192 + 131072) {
        int u = t - (8192 + 65536); int c = u >> 9, r = u & 511;
        Wt2[u] = f2bf(W2[r * 128 + c]);
    } else if (t < 8192 + 131072 + 2048) {
        int u = t - (8192 + 131072); int c = u >> 7, k = u & 127;
        Wz[u] = f2bf(W3[(c >> 2) * 512 + k * 4 + (c & 3)]);
    } else if (t < 8192 + 131072 + 2048 + nx8) {
        int u = t - (8192 + 131072 + 2048);
        float4 v0 = *reinterpret_cast<const float4*>(&x[u * 8]);
        float4 v1 = *reinterpret_cast<const float4*>(&x[u * 8 + 4]);
        uint4 o;
        o.x = pack2bf(v0.x, v0.y); o.y = pack2bf(v0.z, v0.w);
        o.z = pack2bf(v1.x, v1.y); o.w = pack2bf(v1.z, v1.w);
        *reinterpret_cast<uint4*>(&H0[u * 8]) = o;
    }
}

// ---------------- prop d=16: one node/wave, 16 edges x 4 lanes, compact stride 16 ----------------
__global__ __launch_bounds__(256) void k_prop16b(const unsigned short* __restrict__ hin,
                                                 unsigned short* __restrict__ bout,
                                                 const int* __restrict__ row_ptr,
                                                 const unsigned int* __restrict__ csr, int N) {
    int node = blockIdx.x * 4 + (threadIdx.x >> 6);
    if (node >= N) return;
    int lane = threadIdx.x & 63;
    int esub = lane >> 2, f4 = (lane & 3) * 4;
    int s = row_ptr[node], e = row_ptr[node + 1];
    float a0 = 0.f, a1 = 0.f, a2 = 0.f, a3 = 0.f;
    for (int i = s + esub; i < e; i += 16) {
        unsigned int ed = csr[i];
        float w = csr_w(ed);
        uint2 r = *reinterpret_cast<const uint2*>(&hin[(size_t)csr_src(ed) * 16 + f4]);
        a0 += w * bflo(r.x); a1 += w * bfhi(r.x);
        a2 += w * bflo(r.y); a3 += w * bfhi(r.y);
    }
    #pragma unroll
    for (int m = 4; m <= 32; m <<= 1) {
        a0 += __shfl_xor(a0, m); a1 += __shfl_xor(a1, m);
        a2 += __shfl_xor(a2, m); a3 += __shfl_xor(a3, m);
    }
    if (lane < 4) {
        uint2 ob; ob.x = pack2bf(a0, a1); ob.y = pack2bf(a2, a3);
        *reinterpret_cast<uint2*>(&bout[(size_t)node * 16 + f4]) = ob;
    }
}

// ---------------- prop d=128: one node/wave, 16 edges in flight (4/lane) ----------------
__global__ __launch_bounds__(256) void k_prop128b(const unsigned short* __restrict__ hin, int gs,
                                                  unsigned short* __restrict__ bout, int os,
                                                  const int* __restrict__ row_ptr,
                                                  const unsigned int* __restrict__ csr, int N) {
    int node = blockIdx.x * 4 + (threadIdx.x >> 6);
    if (node >= N) return;
    int lane = threadIdx.x & 63;
    int esub = lane >> 4, f8 = (lane & 15) * 8;
    int s = row_ptr[node], e = row_ptr[node + 1];
    float a0 = 0.f, a1 = 0.f, a2 = 0.f, a3 = 0.f;
    float a4 = 0.f, a5 = 0.f, a6 = 0.f, a7 = 0.f;
    int i = s;
    for (; i + 16 <= e; i += 16) {
        unsigned int e0 = csr[i + esub],     e1 = csr[i + esub + 4];
        unsigned int e2 = csr[i + esub + 8], e3 = csr[i + esub + 12];
        uint4 r0 = *reinterpret_cast<const uint4*>(&hin[(size_t)csr_src(e0) * gs + f8]);
        uint4 r1 = *reinterpret_cast<const uint4*>(&hin[(size_t)csr_src(e1) * gs + f8]);
        uint4 r2 = *reinterpret_cast<const uint4*>(&hin[(size_t)csr_src(e2) * gs + f8]);
        uint4 r3 = *reinterpret_cast<const uint4*>(&hin[(size_t)csr_src(e3) * gs + f8]);
        float w0 = csr_w(e0), w1 = csr_w(e1), w2 = csr_w(e2), w3 = csr_w(e3);
        a0 += w0 * bflo(r0.x) + w1 * bflo(r1.x) + w2 * bflo(r2.x) + w3 * bflo(r3.x);
        a1 += w0 * bfhi(r0.x) + w1 * bfhi(r1.x) + w2 * bfhi(r2.x) + w3 * bfhi(r3.x);
        a2 += w0 * bflo(r0.y) + w1 * bflo(r1.y) + w2 * bflo(r2.y) + w3 * bflo(r3.y);
        a3 += w0 * bfhi(r0.y) + w1 * bfhi(r1.y) + w2 * bfhi(r2.y) + w3 * bfhi(r3.y);
        a4 += w0 * bflo(r0.z) + w1 * bflo(r1.z) + w2 * bflo(r2.z) + w3 * bflo(r3.z);
        a5 += w0 * bfhi(r0.z) + w1 * bfhi(r1.z) + w2 * bfhi(r2.z) + w3 * bfhi(r3.z);
        a6 += w0 * bflo(r0.w) + w1 * bflo(r1.w) + w2 * bflo(r2.w) + w3 * bflo(r3.w);
        a7 += w0 * bfhi(r0.w) + w1 * bfhi(r1.w) + w2 * bfhi(r2.w) + w3 * bfhi(r3.w);
    }
    for (int ii = i + esub; ii < e; ii += 4) {
        unsigned int ed = csr[ii];
        float w = csr_w(ed);
        uint4 r = *reinterpret_cast<const uint4*>(&hin[(size_t)csr_src(ed) * gs + f8]);
        a0 += w * bflo(r.x); a1 += w * bfhi(r.x);
        a2 += w * bflo(r.y); a3 += w * bfhi(r.y);
        a4 += w * bflo(r.z); a5 += w * bfhi(r.z);
        a6 += w * bflo(r.w); a7 += w * bfhi(r.w);
    }
    #pragma unroll
    for (int m = 16; m <= 32; m <<= 1) {
        a0 += __shfl_xor(a0, m); a1 += __shfl_xor(a1, m);
        a2 += __shfl_xor(a2, m); a3 += __shfl_xor(a3, m);
        a4 += __shfl_xor(a4, m); a5 += __shfl_xor(a5, m);
        a6 += __shfl_xor(a6, m); a7 += __shfl_xor(a7, m);
    }
    if (lane < 16) {
        uint4 ob;
        ob.x = pack2bf(a0, a1); ob.y = pack2bf(a2, a3);
        ob.z = pack2bf(a4, a5); ob.w = pack2bf(a6, a7);
        *reinterpret_cast<uint4*>(&bout[(size_t)node * os + f8]) = ob;
    }
}

// ---------------- prop d=4 with add: 16 lanes/node, 4 edges parallel ----------------
__global__ __launch_bounds__(256) void k_prop4_add(const float* __restrict__ tin,
                                                   const float* __restrict__ zadd,
                                                   const float* __restrict__ bias,
                                                   float* __restrict__ tout,
                                                   const int* __restrict__ row_ptr,
                                                   const unsigned int* __restrict__ csr, int N) {
    int node = blockIdx.x * 16 + (threadIdx.x >> 4);
    if (node >= N) return;
    int lane = threadIdx.x & 15;
    int esub = lane >> 2, j = lane & 3;
    int s = row_ptr[node], e = row_ptr[node + 1];
    float a = 0.f;
    for (int i = s + esub; i < e; i += 4) {
        unsigned int ed = csr[i];
        a += csr_w(ed) * tin[(size_t)csr_src(ed) * 4 + j];
    }
    a += __shfl_xor(a, 4);
    a += __shfl_xor(a, 8);
    if (esub == 0) {
        float v = a + zadd[(size_t)node * 4 + j];
        if (bias) v += bias[j];
        tout[(size_t)node * 4 + j] = v;
    }
}

// ---------------- MFMA GEMM: C(Mx128)bf16 = relu(A(MxK)bf16 @ Bt(128xK)^T + bias) ----------------
// A and B staged in LDS (R9 form). A from 4 hop buffers: !L0 -> hop = kt>>7; L0 -> hop = off>>4.
// FUSEZ: Z planes (4 x N x 4 fp32) = relu'd-h @ Wz^T via LDS round-trip; Cout write skipped.
template <bool L0, bool FUSEZ>
__global__ __launch_bounds__(256) void k_mfma_gemm(const unsigned short* __restrict__ a0p, int s0,
                                                   const unsigned short* __restrict__ a1p, int s1,
                                                   const unsigned short* __restrict__ a2p, int s2,
                                                   const unsigned short* __restrict__ a3p, int s3,
                                                   int K,
                                                   const unsigned short* __restrict__ Bt,
                                                   const float* __restrict__ bias,
                                                   unsigned short* __restrict__ Coutb,
                                                   const unsigned short* __restrict__ Wzg,
                                                   float* __restrict__ Zout, int M) {
    __shared__ unsigned short smem[19584];   // As[128][72] | Bs[128][72]; reused as Hs[128][136] + WzS[16][136]
    unsigned short (*As)[72] = reinterpret_cast<unsigned short(*)[72]>(smem);
    unsigned short (*Bs)[72] = reinterpret_cast<unsigned short(*)[72]>(smem + 9216);
    const unsigned short* Ab[4] = { a0p, a1p, a2p, a3p };
    int Ast[4] = { s0, s1, s2, s3 };
    int tid = threadIdx.x;
    int r0 = blockIdx.x * 128;
    int wid = tid >> 6, lane = tid & 63;
    int wm = (wid >> 1) * 64, wn = (wid & 1) * 64;
    f32x4v acc[4][4];
    #pragma unroll
    for (int a = 0; a < 4; ++a)
        #pragma unroll
        for (int b = 0; b < 4; ++b) acc[a][b] = (f32x4v){0.f, 0.f, 0.f, 0.f};

    int rsel = lane & 15, ksel = (lane >> 4) * 8;

    for (int kt = 0; kt < K; kt += 64) {
        #pragma unroll
        for (int i = 0; i < 4; ++i) {
            int c = tid + i * 256;
            int row = c >> 3, off = (c & 7) * 8;
            int gr = r0 + row;
            int4 v = make_int4(0, 0, 0, 0);
            if (L0) {
                int hop = off >> 4, col0 = off & 15;
                if (gr < M) v = *reinterpret_cast<const int4*>(Ab[hop] + (size_t)gr * 16 + col0);
            } else {
                int hop = kt >> 7, kb = kt & 127;
                if (gr < M) v = *reinterpret_cast<const int4*>(Ab[hop] + (size_t)gr * Ast[hop] + kb + off);
            }
            *reinterpret_cast<int4*>(&As[row][off]) = v;
            int4 w = *reinterpret_cast<const int4*>(Bt + (size_t)row * K + kt + off);
            *reinterpret_cast<int4*>(&Bs[row][off]) = w;
        }
        __syncthreads();
        #pragma unroll
        for (int kc = 0; kc < 64; kc += 32) {
            bf16x8v af[4], bfv[4];
            #pragma unroll
            for (int f = 0; f < 4; ++f) {
                af[f]  = *reinterpret_cast<const bf16x8v*>(&As[wm + f * 16 + rsel][kc + ksel]);
                bfv[f] = *reinterpret_cast<const bf16x8v*>(&Bs[wn + f * 16 + rsel][kc + ksel]);
            }
            #pragma unroll
            for (int mf = 0; mf < 4; ++mf)
                #pragma unroll
                for (int nf = 0; nf < 4; ++nf)
                    acc[mf][nf] = __builtin_amdgcn_mfma_f32_16x16x32_bf16(af[mf], bfv[nf], acc[mf][nf], 0, 0, 0);
        }
        __syncthreads();
    }
    // epilogue: C/D layout col=lane&15, row=(lane>>4)*4+reg
    int col_l = lane & 15, rgrp = (lane >> 4) * 4;
    unsigned short* Hs = smem;              // [128][136]
    unsigned short* WzS = smem + 17408;     // [16][136]
    #pragma unroll
    for (int nf = 0; nf < 4; ++nf) {
        int col = wn + nf * 16 + col_l;
        float bv = bias[col];
        #pragma unroll
        for (int mf = 0; mf < 4; ++mf) {
            #pragma unroll
            for (int j = 0; j < 4; ++j) {
                int lrow = wm + mf * 16 + rgrp + j;
                float v = fmaxf(acc[mf][nf][j] + bv, 0.f);
                unsigned short hb = f2bf(v);
                if (FUSEZ) {
                    Hs[lrow * 136 + col] = hb;
                } else {
                    int row = r0 + lrow;
                    if (row < M) Coutb[(size_t)row * 128 + col] = hb;
                }
            }
        }
    }
    if (FUSEZ) {
        for (int t = tid; t < 2048; t += 256) {
            WzS[(t >> 7) * 136 + (t & 127)] = Wzg[t];
        }
        __syncthreads();
        int wmz = wid * 32;
        f32x4v z0 = (f32x4v){0.f, 0.f, 0.f, 0.f};
        f32x4v z1 = (f32x4v){0.f, 0.f, 0.f, 0.f};
        #pragma unroll
        for (int kt2 = 0; kt2 < 128; kt2 += 32) {
            bf16x8v aa0 = *reinterpret_cast<const bf16x8v*>(&Hs[(wmz + rsel) * 136 + kt2 + ksel]);
            bf16x8v aa1 = *reinterpret_cast<const bf16x8v*>(&Hs[(wmz + 16 + rsel) * 136 + kt2 + ksel]);
            bf16x8v bz = *reinterpret_cast<const bf16x8v*>(&WzS[rsel * 136 + kt2 + ksel]);
            z0 = __builtin_amdgcn_mfma_f32_16x16x32_bf16(aa0, bz, z0, 0, 0, 0);
            z1 = __builtin_amdgcn_mfma_f32_16x16x32_bf16(aa1, bz, z1, 0, 0, 0);
        }
        // Z planes: plane = col>>2, within-plane col = col&3
        size_t plane = (size_t)(col_l >> 2) * (size_t)M * 4;
        int cj = col_l & 3;
        #pragma unroll
        for (int j = 0; j < 4; ++j) {
            int ra = r0 + wmz + rgrp + j;
            if (ra < M) Zout[plane + (size_t)ra * 4 + cj] = z0[j];
            int rb = r0 + wmz + 16 + rgrp + j;
            if (rb < M) Zout[plane + (size_t)rb * 4 + cj] = z1[j];
        }
    }
}

// ---------------- launch ----------------
extern "C" void kernel_launch(void* const* d_in, const int* in_sizes, int n_in,
                              void* d_out, int out_size, void* d_ws, size_t ws_size,
                              hipStream_t stream) {
    const float* x  = (const float*)d_in[0];
    const int*   ei = (const int*)d_in[1];
    const float* ew = (const float*)d_in[2];
    const float* W0 = (const float*)d_in[3];
    const float* b0 = (const float*)d_in[4];
    const float* W1 = (const float*)d_in[5];
    const float* b1 = (const float*)d_in[6];
    const float* W2 = (const float*)d_in[7];
    const float* b2 = (const float*)d_in[8];
    const float* W3 = (const float*)d_in[9];
    const float* b3 = (const float*)d_in[10];
    float* out = (float*)d_out;

    const int N = in_sizes[0] / 16;   // 100000
    const int E = in_sizes[2];        // 3200000
    const int* src = ei;
    const int* dst = ei + E;

    char* ws = (char*)d_ws;
    size_t off = 0;
    auto take = [&](size_t bytes) -> void* {
        void* p = ws + off;
        off = (off + bytes + 255) & ~(size_t)255;
        return p;
    };
    unsigned short* S   = (unsigned short*)take((size_t)N * 384 * 2);  // hop slots 1..3 (stride 384)
    unsigned short* Qa  = (unsigned short*)take((size_t)N * 128 * 2);
    unsigned short* Qb  = (unsigned short*)take((size_t)N * 128 * 2);
    unsigned short* H0  = (unsigned short*)take((size_t)N * 16 * 2);  // layer-0 compact hops
    unsigned short* H1  = (unsigned short*)take((size_t)N * 16 * 2);
    unsigned short* H2  = (unsigned short*)take((size_t)N * 16 * 2);
    unsigned short* H3  = (unsigned short*)take((size_t)N * 16 * 2);
    unsigned int*  csr  = (unsigned int*) take((size_t)E * 4);        // packed (src<<15)|bf16w15
    unsigned long long* dc = (unsigned long long*)take((size_t)N * 8);
    unsigned short* rank = (unsigned short*)take((size_t)E * 2);
    float* dis     = (float*)take((size_t)N * 4);
    int*   row_ptr = (int*)  take((size_t)(N + 1) * 4);
    int*   bsum    = (int*)  take(1024);
    float* Z       = (float*)take((size_t)N * 16 * 4);   // 4 planes of N x 4
    float* T1      = (float*)take((size_t)N * 4 * 4);
    float* T2      = (float*)take((size_t)N * 4 * 4);
    unsigned short* Wt0 = (unsigned short*)take(64 * 128 * 2);
    unsigned short* Wt1 = (unsigned short*)take(512 * 128 * 2);
    unsigned short* Wt2 = (unsigned short*)take(512 * 128 * 2);
    unsigned short* Wz  = (unsigned short*)take(16 * 128 * 2);

    // ---- build norm + CSR (one packed atomic pass, atomic-free fill) ----
    hipMemsetAsync(dc, 0, (size_t)N * 8, stream);
    k_edge_deg<<<2048, 256, 0, stream>>>(dst, ew, dc, rank, E);
    int nsb = (N + 1023) / 1024;
    k_scan1<<<nsb, 256, 0, stream>>>(dc, bsum, dis, N);
    k_scan3<<<nsb, 256, 0, stream>>>(dc, bsum, row_ptr, N, nsb);
    k_fill_csr<<<2048, 256, 0, stream>>>(src, dst, ew, dis, row_ptr, rank, csr, E);

    // ---- weight prep + x cast (one kernel) ----
    int nx8 = N * 2;
    k_wprep_all<<<(141312 + nx8 + 255) / 256, 256, 0, stream>>>(W0, W1, W2, W3, x,
                                                                Wt0, Wt1, Wt2, Wz, H0, nx8);

    int gmfma = (N + 127) / 128;
    int gpw   = (N + 3) / 4;      // one node per wave, 4 waves/block
    size_t N4 = (size_t)N * 4;

    // ---- layer 0: 16 -> 128 (compact bf16 hop chain H0..H3) ----
    k_prop16b<<<gpw, 256, 0, stream>>>(H0, H1, row_ptr, csr, N);
    k_prop16b<<<gpw, 256, 0, stream>>>(H1, H2, row_ptr, csr, N);
    k_prop16b<<<gpw, 256, 0, stream>>>(H2, H3, row_ptr, csr, N);
    k_mfma_gemm<true, false><<<gmfma, 256, 0, stream>>>(H0, 16, H1, 16, H2, 16, H3, 16,
                                                        64, Wt0, b0, Qa, nullptr, nullptr, N);

    // ---- layer 1: 128 -> 128 ----
    k_prop128b<<<gpw, 256, 0, stream>>>(Qa, 128,      S + 0,   384, row_ptr, csr, N);
    k_prop128b<<<gpw, 256, 0, stream>>>(S + 0, 384,   S + 128, 384, row_ptr, csr, N);
    k_prop128b<<<gpw, 256, 0, stream>>>(S + 128, 384, S + 256, 384, row_ptr, csr, N);
    k_mfma_gemm<false, false><<<gmfma, 256, 0, stream>>>(Qa, 128, S + 0, 384, S + 128, 384, S + 256, 384,
                                                         512, Wt1, b1, Qb, nullptr, nullptr, N);

    // ---- layer 2: 128 -> 128, Z fused into epilogue ----
    k_prop128b<<<gpw, 256, 0, stream>>>(Qb, 128,      S + 0,   384, row_ptr, csr, N);
    k_prop128b<<<gpw, 256, 0, stream>>>(S + 0, 384,   S + 128, 384, row_ptr, csr, N);
    k_prop128b<<<gpw, 256, 0, stream>>>(S + 128, 384, S + 256, 384, row_ptr, csr, N);
    k_mfma_gemm<false, true><<<gmfma, 256, 0, stream>>>(Qb, 128, S + 0, 384, S + 128, 384, S + 256, 384,
                                                        512, Wt2, b2, nullptr, Wz, Z, N);

    // ---- layer 3: 128 -> 4 via projected Horner on Z planes ----
    {
        int g = (N + 15) / 16;
        k_prop4_add<<<g, 256, 0, stream>>>(Z + 3 * N4, Z + 2 * N4, nullptr, T1, row_ptr, csr, N);
        k_prop4_add<<<g, 256, 0, stream>>>(T1,         Z + 1 * N4, nullptr, T2, row_ptr, csr, N);
        k_prop4_add<<<g, 256, 0, stream>>>(T2,         Z + 0 * N4, b3,      out, row_ptr, csr, N);
    }
}

// Round 13
// 1133.996 us; speedup vs baseline: 1.0606x; 1.0161x over previous
//
#include <hip/hip_runtime.h>

// TAGConv L3: N=100000, E=3200000, K=3. dims (16->128)(128->128)(128->128)(128->4).
// R12: GEMM staging via __builtin_amdgcn_global_load_lds (width 16) into LINEAR LDS
//      with chunk-XOR swizzle (cc ^= row&7) applied to BOTH the per-lane global source
//      and the ds_read address (rule: both-sides-or-neither). No reg->LDS round trip.
//      Else = R11: packed 4B CSR, compact hop buffers, one-node-per-wave props,
//      Z-fused layer-2 GEMM, packed-u64 atomic CSR build, d=4 Horner layer 3.

typedef __attribute__((ext_vector_type(8))) short bf16x8v;   // 8 bf16 = 4 VGPR
typedef __attribute__((ext_vector_type(4))) float f32x4v;

__device__ __forceinline__ float bflo(unsigned int u) { return __uint_as_float(u << 16); }
__device__ __forceinline__ float bfhi(unsigned int u) { return __uint_as_float(u & 0xffff0000u); }
__device__ __forceinline__ unsigned short f2bf(float f) {
    unsigned int u = __float_as_uint(f);
    u = (u + 0x7fff + ((u >> 16) & 1)) >> 16;   // RNE
    return (unsigned short)u;
}
__device__ __forceinline__ unsigned int pack2bf(float lo, float hi) {
    return (unsigned int)f2bf(lo) | ((unsigned int)f2bf(hi) << 16);
}
// packed CSR decode
__device__ __forceinline__ unsigned int csr_src(unsigned int v) { return v >> 15; }
__device__ __forceinline__ float csr_w(unsigned int v) { return __uint_as_float((v & 0x7FFFu) << 16); }
// async global->LDS, 16B per lane (dest = wave-uniform base + lane*16)
__device__ __forceinline__ void gload_lds16(const unsigned short* g, unsigned short* l) {
    __builtin_amdgcn_global_load_lds((const __attribute__((address_space(1))) void*)g,
                                     (__attribute__((address_space(3))) void*)l, 16, 0, 0);
}

// ---------------- pass 1: packed deg/count atomic + per-edge rank ----------------
__global__ void k_edge_deg(const int* __restrict__ dst, const float* __restrict__ ew,
                           unsigned long long* __restrict__ dc,
                           unsigned short* __restrict__ rank, int E) {
    int stride = gridDim.x * blockDim.x;
    for (int e = blockIdx.x * blockDim.x + threadIdx.x; e < E; e += stride) {
        int d = dst[e];
        unsigned long long fx = (unsigned long long)(ew[e] * 0x1p40f);
        unsigned long long old = atomicAdd(&dc[d], (fx << 12) | 1ULL);
        rank[e] = (unsigned short)(old & 0xFFFULL);
    }
}

// ---------------- scan phase 1 (+ dis fused) ----------------
__global__ void k_scan1(const unsigned long long* __restrict__ dc, int* __restrict__ bsum,
                        float* __restrict__ dis, int N) {
    __shared__ int s[256];
    int tid = threadIdx.x;
    int base = blockIdx.x * 1024 + tid * 4;
    int t = 0;
    #pragma unroll
    for (int i = 0; i < 4; ++i) {
        int idx = base + i;
        if (idx < N) {
            unsigned long long v = dc[idx];
            t += (int)(v & 0xFFFULL);
            float d = (float)(v >> 12) * 0x1p-40f;
            dis[idx] = d > 0.f ? rsqrtf(d) : 0.f;
        }
    }
    s[tid] = t; __syncthreads();
    for (int off = 128; off > 0; off >>= 1) {
        if (tid < off) s[tid] += s[tid + off];
        __syncthreads();
    }
    if (tid == 0) bsum[blockIdx.x] = s[0];
}

// ---------------- scan phase 2: row_ptr, with in-block prefix over bsum ----------------
__global__ void k_scan3(const unsigned long long* __restrict__ dc, const int* __restrict__ bsum,
                        int* __restrict__ row_ptr, int N, int nsb) {
    __shared__ int s[256];
    __shared__ int blockoff;
    int tid = threadIdx.x;
    s[tid] = (tid < blockIdx.x && tid < nsb) ? bsum[tid] : 0;
    __syncthreads();
    for (int off = 128; off > 0; off >>= 1) {
        if (tid < off) s[tid] += s[tid + off];
        __syncthreads();
    }
    if (tid == 0) blockoff = s[0];
    __syncthreads();

    int base = blockIdx.x * 1024 + tid * 4;
    int v[4]; int t = 0;
    #pragma unroll
    for (int i = 0; i < 4; ++i) { int idx = base + i; v[i] = (idx < N) ? (int)(dc[idx] & 0xFFFULL) : 0; t += v[i]; }
    s[tid] = t; __syncthreads();
    for (int off = 1; off < 256; off <<= 1) {
        int add = (tid >= off) ? s[tid - off] : 0;
        __syncthreads();
        s[tid] += add;
        __syncthreads();
    }
    int g = blockoff + (s[tid] - t);   // exclusive prefix
    #pragma unroll
    for (int i = 0; i < 4; ++i) {
        int idx = base + i;
        if (idx < N) row_ptr[idx] = g;
        g += v[i];
    }
    if (blockIdx.x == nsb - 1 && tid == 255) row_ptr[N] = blockoff + s[255];
}

// ---------------- pass 2: atomic-free CSR fill (packed 4B entries) ----------------
__global__ void k_fill_csr(const int* __restrict__ src, const int* __restrict__ dst,
                           const float* __restrict__ ew, const float* __restrict__ dis,
                           const int* __restrict__ row_ptr, const unsigned short* __restrict__ rank,
                           unsigned int* __restrict__ csr, int E) {
    int stride = gridDim.x * blockDim.x;
    for (int e = blockIdx.x * blockDim.x + threadIdx.x; e < E; e += stride) {
        int d = dst[e];
        unsigned int s = (unsigned int)src[e];
        int pos = row_ptr[d] + rank[e];
        float w = dis[s] * ew[e] * dis[d];
        csr[pos] = (s << 15) | ((unsigned int)f2bf(w) & 0x7FFFu);
    }
}

// ---------------- weight prep + x cast (one kernel) ----------------
__global__ void k_wprep_all(const float* __restrict__ W0, const float* __restrict__ W1,
                            const float* __restrict__ W2, const float* __restrict__ W3,
                            const float* __restrict__ x,
                            unsigned short* __restrict__ Wt0, unsigned short* __restrict__ Wt1,
                            unsigned short* __restrict__ Wt2, unsigned short* __restrict__ Wz,
                            unsigned short* __restrict__ H0, int nx8) {
    int t = blockIdx.x * blockDim.x + threadIdx.x;
    if (t < 8192) {
        int c = t >> 6, r = t & 63;
        Wt0[t] = f2bf(W0[r * 128 + c]);
    } else if (t < 8192 + 65536) {
        int u = t - 8192; int c = u >> 9, r = u & 511;
        Wt1[u] = f2bf(W1[r * 128 + c]);
    } else if (t < 8192 + 131072) {
        int u = t - (8192 + 65536); int c = u >> 9, r = u & 511;
        Wt2[u] = f2bf(W2[r * 128 + c]);
    } else if (t < 8192 + 131072 + 2048) {
        int u = t - (8192 + 131072); int c = u >> 7, k = u & 127;
        Wz[u] = f2bf(W3[(c >> 2) * 512 + k * 4 + (c & 3)]);
    } else if (t < 8192 + 131072 + 2048 + nx8) {
        int u = t - (8192 + 131072 + 2048);
        float4 v0 = *reinterpret_cast<const float4*>(&x[u * 8]);
        float4 v1 = *reinterpret_cast<const float4*>(&x[u * 8 + 4]);
        uint4 o;
        o.x = pack2bf(v0.x, v0.y); o.y = pack2bf(v0.z, v0.w);
        o.z = pack2bf(v1.x, v1.y); o.w = pack2bf(v1.z, v1.w);
        *reinterpret_cast<uint4*>(&H0[u * 8]) = o;
    }
}

// ---------------- prop d=16: one node/wave, 16 edges x 4 lanes, compact stride 16 ----------------
__global__ __launch_bounds__(256) void k_prop16b(const unsigned short* __restrict__ hin,
                                                 unsigned short* __restrict__ bout,
                                                 const int* __restrict__ row_ptr,
                                                 const unsigned int* __restrict__ csr, int N) {
    int node = blockIdx.x * 4 + (threadIdx.x >> 6);
    if (node >= N) return;
    int lane = threadIdx.x & 63;
    int esub = lane >> 2, f4 = (lane & 3) * 4;
    int s = row_ptr[node], e = row_ptr[node + 1];
    float a0 = 0.f, a1 = 0.f, a2 = 0.f, a3 = 0.f;
    for (int i = s + esub; i < e; i += 16) {
        unsigned int ed = csr[i];
        float w = csr_w(ed);
        uint2 r = *reinterpret_cast<const uint2*>(&hin[(size_t)csr_src(ed) * 16 + f4]);
        a0 += w * bflo(r.x); a1 += w * bfhi(r.x);
        a2 += w * bflo(r.y); a3 += w * bfhi(r.y);
    }
    #pragma unroll
    for (int m = 4; m <= 32; m <<= 1) {
        a0 += __shfl_xor(a0, m); a1 += __shfl_xor(a1, m);
        a2 += __shfl_xor(a2, m); a3 += __shfl_xor(a3, m);
    }
    if (lane < 4) {
        uint2 ob; ob.x = pack2bf(a0, a1); ob.y = pack2bf(a2, a3);
        *reinterpret_cast<uint2*>(&bout[(size_t)node * 16 + f4]) = ob;
    }
}

// ---------------- prop d=128: one node/wave, 16 edges in flight (4/lane) ----------------
__global__ __launch_bounds__(256) void k_prop128b(const unsigned short* __restrict__ hin, int gs,
                                                  unsigned short* __restrict__ bout, int os,
                                                  const int* __restrict__ row_ptr,
                                                  const unsigned int* __restrict__ csr, int N) {
    int node = blockIdx.x * 4 + (threadIdx.x >> 6);
    if (node >= N) return;
    int lane = threadIdx.x & 63;
    int esub = lane >> 4, f8 = (lane & 15) * 8;
    int s = row_ptr[node], e = row_ptr[node + 1];
    float a0 = 0.f, a1 = 0.f, a2 = 0.f, a3 = 0.f;
    float a4 = 0.f, a5 = 0.f, a6 = 0.f, a7 = 0.f;
    int i = s;
    for (; i + 16 <= e; i += 16) {
        unsigned int e0 = csr[i + esub],     e1 = csr[i + esub + 4];
        unsigned int e2 = csr[i + esub + 8], e3 = csr[i + esub + 12];
        uint4 r0 = *reinterpret_cast<const uint4*>(&hin[(size_t)csr_src(e0) * gs + f8]);
        uint4 r1 = *reinterpret_cast<const uint4*>(&hin[(size_t)csr_src(e1) * gs + f8]);
        uint4 r2 = *reinterpret_cast<const uint4*>(&hin[(size_t)csr_src(e2) * gs + f8]);
        uint4 r3 = *reinterpret_cast<const uint4*>(&hin[(size_t)csr_src(e3) * gs + f8]);
        float w0 = csr_w(e0), w1 = csr_w(e1), w2 = csr_w(e2), w3 = csr_w(e3);
        a0 += w0 * bflo(r0.x) + w1 * bflo(r1.x) + w2 * bflo(r2.x) + w3 * bflo(r3.x);
        a1 += w0 * bfhi(r0.x) + w1 * bfhi(r1.x) + w2 * bfhi(r2.x) + w3 * bfhi(r3.x);
        a2 += w0 * bflo(r0.y) + w1 * bflo(r1.y) + w2 * bflo(r2.y) + w3 * bflo(r3.y);
        a3 += w0 * bfhi(r0.y) + w1 * bfhi(r1.y) + w2 * bfhi(r2.y) + w3 * bfhi(r3.y);
        a4 += w0 * bflo(r0.z) + w1 * bflo(r1.z) + w2 * bflo(r2.z) + w3 * bflo(r3.z);
        a5 += w0 * bfhi(r0.z) + w1 * bfhi(r1.z) + w2 * bfhi(r2.z) + w3 * bfhi(r3.z);
        a6 += w0 * bflo(r0.w) + w1 * bflo(r1.w) + w2 * bflo(r2.w) + w3 * bflo(r3.w);
        a7 += w0 * bfhi(r0.w) + w1 * bfhi(r1.w) + w2 * bfhi(r2.w) + w3 * bfhi(r3.w);
    }
    for (int ii = i + esub; ii < e; ii += 4) {
        unsigned int ed = csr[ii];
        float w = csr_w(ed);
        uint4 r = *reinterpret_cast<const uint4*>(&hin[(size_t)csr_src(ed) * gs + f8]);
        a0 += w * bflo(r.x); a1 += w * bfhi(r.x);
        a2 += w * bflo(r.y); a3 += w * bfhi(r.y);
        a4 += w * bflo(r.z); a5 += w * bfhi(r.z);
        a6 += w * bflo(r.w); a7 += w * bfhi(r.w);
    }
    #pragma unroll
    for (int m = 16; m <= 32; m <<= 1) {
        a0 += __shfl_xor(a0, m); a1 += __shfl_xor(a1, m);
        a2 += __shfl_xor(a2, m); a3 += __shfl_xor(a3, m);
        a4 += __shfl_xor(a4, m); a5 += __shfl_xor(a5, m);
        a6 += __shfl_xor(a6, m); a7 += __shfl_xor(a7, m);
    }
    if (lane < 16) {
        uint4 ob;
        ob.x = pack2bf(a0, a1); ob.y = pack2bf(a2, a3);
        ob.z = pack2bf(a4, a5); ob.w = pack2bf(a6, a7);
        *reinterpret_cast<uint4*>(&bout[(size_t)node * os + f8]) = ob;
    }
}

// ---------------- prop d=4 with add: 16 lanes/node, 4 edges parallel ----------------
__global__ __launch_bounds__(256) void k_prop4_add(const float* __restrict__ tin,
                                                   const float* __restrict__ zadd,
                                                   const float* __restrict__ bias,
                                                   float* __restrict__ tout,
                                                   const int* __restrict__ row_ptr,
                                                   const unsigned int* __restrict__ csr, int N) {
    int node = blockIdx.x * 16 + (threadIdx.x >> 4);
    if (node >= N) return;
    int lane = threadIdx.x & 15;
    int esub = lane >> 2, j = lane & 3;
    int s = row_ptr[node], e = row_ptr[node + 1];
    float a = 0.f;
    for (int i = s + esub; i < e; i += 4) {
        unsigned int ed = csr[i];
        a += csr_w(ed) * tin[(size_t)csr_src(ed) * 4 + j];
    }
    a += __shfl_xor(a, 4);
    a += __shfl_xor(a, 8);
    if (esub == 0) {
        float v = a + zadd[(size_t)node * 4 + j];
        if (bias) v += bias[j];
        tout[(size_t)node * 4 + j] = v;
    }
}

// ---------------- MFMA GEMM: C(Mx128)bf16 = relu(A(MxK)bf16 @ Bt(128xK)^T + bias) ----------------
// Staging: global_load_lds width=16 into LINEAR LDS [128][64] per operand; chunk swizzle
// cc_lds holds logical chunk (cc ^ (row&7)) -> source address inverse-permuted, reader XORs.
// A from 4 hop buffers: !L0 -> hop = kt>>7; L0 -> hop = ccs>>1, col = (ccs&1)*8 (K=64).
// FUSEZ: Z planes (4 x N x 4 fp32) = relu'd-h @ Wz^T via LDS round-trip; Cout write skipped.
template <bool L0, bool FUSEZ>
__global__ __launch_bounds__(256) void k_mfma_gemm(const unsigned short* __restrict__ a0p, int s0,
                                                   const unsigned short* __restrict__ a1p, int s1,
                                                   const unsigned short* __restrict__ a2p, int s2,
                                                   const unsigned short* __restrict__ a3p, int s3,
                                                   int K,
                                                   const unsigned short* __restrict__ Bt,
                                                   const float* __restrict__ bias,
                                                   unsigned short* __restrict__ Coutb,
                                                   const unsigned short* __restrict__ Wzg,
                                                   float* __restrict__ Zout, int M) {
    __shared__ unsigned short smem[19584];   // As_lin[8192] | Bs_lin[8192]; reused as Hs[128][136] + WzS[16][136]
    unsigned short* As_lin = smem;           // [128 rows][8 chunks of 8 bf16]
    unsigned short* Bs_lin = smem + 8192;
    const unsigned short* Ab[4] = { a0p, a1p, a2p, a3p };
    int Ast[4] = { s0, s1, s2, s3 };
    int tid = threadIdx.x;
    int r0 = blockIdx.x * 128;
    int wid = tid >> 6, lane = tid & 63;
    int wm = (wid >> 1) * 64, wn = (wid & 1) * 64;
    f32x4v acc[4][4];
    #pragma unroll
    for (int a = 0; a < 4; ++a)
        #pragma unroll
        for (int b = 0; b < 4; ++b) acc[a][b] = (f32x4v){0.f, 0.f, 0.f, 0.f};

    int rsel = lane & 15, ksel = (lane >> 4) * 8;

    for (int kt = 0; kt < K; kt += 64) {
        // stage A and B: 1024 chunks each, 64 chunks per wave-instruction
        #pragma unroll
        for (int i = 0; i < 4; ++i) {
            int c = i * 256 + wid * 64 + lane;        // chunk id 0..1023
            int row = c >> 3, cc = c & 7;
            int ccs = cc ^ (row & 7);                 // logical chunk held at LDS slot cc
            const unsigned short* ga;
            if (L0) {
                int hop = ccs >> 1, col0 = (ccs & 1) * 8;
                ga = Ab[hop] + (size_t)(r0 + row) * 16 + col0;
            } else {
                int hop = kt >> 7, kb = kt & 127;
                ga = Ab[hop] + (size_t)(r0 + row) * Ast[hop] + kb + ccs * 8;
            }
            gload_lds16(ga, &As_lin[(size_t)(i * 256 + wid * 64) * 8]);
            const unsigned short* gb = Bt + (size_t)row * K + kt + ccs * 8;
            gload_lds16(gb, &Bs_lin[(size_t)(i * 256 + wid * 64) * 8]);
        }
        __syncthreads();
        #pragma unroll
        for (int kc = 0; kc < 64; kc += 32) {
            bf16x8v af[4], bfv[4];
            #pragma unroll
            for (int f = 0; f < 4; ++f) {
                int arow = wm + f * 16 + rsel;
                int ach  = ((kc + ksel) >> 3) ^ (arow & 7);
                af[f]  = *reinterpret_cast<const bf16x8v*>(&As_lin[arow * 64 + ach * 8]);
                int brow = wn + f * 16 + rsel;
                int bch  = ((kc + ksel) >> 3) ^ (brow & 7);
                bfv[f] = *reinterpret_cast<const bf16x8v*>(&Bs_lin[brow * 64 + bch * 8]);
            }
            #pragma unroll
            for (int mf = 0; mf < 4; ++mf)
                #pragma unroll
                for (int nf = 0; nf < 4; ++nf)
                    acc[mf][nf] = __builtin_amdgcn_mfma_f32_16x16x32_bf16(af[mf], bfv[nf], acc[mf][nf], 0, 0, 0);
        }
        __syncthreads();
    }
    // epilogue: C/D layout col=lane&15, row=(lane>>4)*4+reg
    int col_l = lane & 15, rgrp = (lane >> 4) * 4;
    unsigned short* Hs = smem;              // [128][136]
    unsigned short* WzS = smem + 17408;     // [16][136]
    #pragma unroll
    for (int nf = 0; nf < 4; ++nf) {
        int col = wn + nf * 16 + col_l;
        float bv = bias[col];
        #pragma unroll
        for (int mf = 0; mf < 4; ++mf) {
            #pragma unroll
            for (int j = 0; j < 4; ++j) {
                int lrow = wm + mf * 16 + rgrp + j;
                float v = fmaxf(acc[mf][nf][j] + bv, 0.f);
                unsigned short hb = f2bf(v);
                if (FUSEZ) {
                    Hs[lrow * 136 + col] = hb;
                } else {
                    int row = r0 + lrow;
                    if (row < M) Coutb[(size_t)row * 128 + col] = hb;
                }
            }
        }
    }
    if (FUSEZ) {
        for (int t = tid; t < 2048; t += 256) {
            WzS[(t >> 7) * 136 + (t & 127)] = Wzg[t];
        }
        __syncthreads();
        int wmz = wid * 32;
        f32x4v z0 = (f32x4v){0.f, 0.f, 0.f, 0.f};
        f32x4v z1 = (f32x4v){0.f, 0.f, 0.f, 0.f};
        #pragma unroll
        for (int kt2 = 0; kt2 < 128; kt2 += 32) {
            bf16x8v aa0 = *reinterpret_cast<const bf16x8v*>(&Hs[(wmz + rsel) * 136 + kt2 + ksel]);
            bf16x8v aa1 = *reinterpret_cast<const bf16x8v*>(&Hs[(wmz + 16 + rsel) * 136 + kt2 + ksel]);
            bf16x8v bz = *reinterpret_cast<const bf16x8v*>(&WzS[rsel * 136 + kt2 + ksel]);
            z0 = __builtin_amdgcn_mfma_f32_16x16x32_bf16(aa0, bz, z0, 0, 0, 0);
            z1 = __builtin_amdgcn_mfma_f32_16x16x32_bf16(aa1, bz, z1, 0, 0, 0);
        }
        // Z planes: plane = col>>2, within-plane col = col&3
        size_t plane = (size_t)(col_l >> 2) * (size_t)M * 4;
        int cj = col_l & 3;
        #pragma unroll
        for (int j = 0; j < 4; ++j) {
            int ra = r0 + wmz + rgrp + j;
            if (ra < M) Zout[plane + (size_t)ra * 4 + cj] = z0[j];
            int rb = r0 + wmz + 16 + rgrp + j;
            if (rb < M) Zout[plane + (size_t)rb * 4 + cj] = z1[j];
        }
    }
}

// ---------------- launch ----------------
extern "C" void kernel_launch(void* const* d_in, const int* in_sizes, int n_in,
                              void* d_out, int out_size, void* d_ws, size_t ws_size,
                              hipStream_t stream) {
    const float* x  = (const float*)d_in[0];
    const int*   ei = (const int*)d_in[1];
    const float* ew = (const float*)d_in[2];
    const float* W0 = (const float*)d_in[3];
    const float* b0 = (const float*)d_in[4];
    const float* W1 = (const float*)d_in[5];
    const float* b1 = (const float*)d_in[6];
    const float* W2 = (const float*)d_in[7];
    const float* b2 = (const float*)d_in[8];
    const float* W3 = (const float*)d_in[9];
    const float* b3 = (const float*)d_in[10];
    float* out = (float*)d_out;

    const int N = in_sizes[0] / 16;   // 100000
    const int E = in_sizes[2];        // 3200000
    const int* src = ei;
    const int* dst = ei + E;

    char* ws = (char*)d_ws;
    size_t off = 0;
    auto take = [&](size_t bytes) -> void* {
        void* p = ws + off;
        off = (off + bytes + 255) & ~(size_t)255;
        return p;
    };
    unsigned short* S   = (unsigned short*)take((size_t)N * 384 * 2);  // hop slots 1..3 (stride 384)
    unsigned short* Qa  = (unsigned short*)take((size_t)N * 128 * 2);
    unsigned short* Qb  = (unsigned short*)take((size_t)N * 128 * 2);
    unsigned short* H0  = (unsigned short*)take((size_t)N * 16 * 2);  // layer-0 compact hops
    unsigned short* H1  = (unsigned short*)take((size_t)N * 16 * 2);
    unsigned short* H2  = (unsigned short*)take((size_t)N * 16 * 2);
    unsigned short* H3  = (unsigned short*)take((size_t)N * 16 * 2);
    unsigned int*  csr  = (unsigned int*) take((size_t)E * 4);        // packed (src<<15)|bf16w15
    unsigned long long* dc = (unsigned long long*)take((size_t)N * 8);
    unsigned short* rank = (unsigned short*)take((size_t)E * 2);
    float* dis     = (float*)take((size_t)N * 4);
    int*   row_ptr = (int*)  take((size_t)(N + 1) * 4);
    int*   bsum    = (int*)  take(1024);
    float* Z       = (float*)take((size_t)N * 16 * 4);   // 4 planes of N x 4
    float* T1      = (float*)take((size_t)N * 4 * 4);
    float* T2      = (float*)take((size_t)N * 4 * 4);
    unsigned short* Wt0 = (unsigned short*)take(64 * 128 * 2);
    unsigned short* Wt1 = (unsigned short*)take(512 * 128 * 2);
    unsigned short* Wt2 = (unsigned short*)take(512 * 128 * 2);
    unsigned short* Wz  = (unsigned short*)take(16 * 128 * 2);

    // ---- build norm + CSR (one packed atomic pass, atomic-free fill) ----
    hipMemsetAsync(dc, 0, (size_t)N * 8, stream);
    k_edge_deg<<<2048, 256, 0, stream>>>(dst, ew, dc, rank, E);
    int nsb = (N + 1023) / 1024;
    k_scan1<<<nsb, 256, 0, stream>>>(dc, bsum, dis, N);
    k_scan3<<<nsb, 256, 0, stream>>>(dc, bsum, row_ptr, N, nsb);
    k_fill_csr<<<2048, 256, 0, stream>>>(src, dst, ew, dis, row_ptr, rank, csr, E);

    // ---- weight prep + x cast (one kernel) ----
    int nx8 = N * 2;
    k_wprep_all<<<(141312 + nx8 + 255) / 256, 256, 0, stream>>>(W0, W1, W2, W3, x,
                                                                Wt0, Wt1, Wt2, Wz, H0, nx8);

    int gmfma = (N + 127) / 128;
    int gpw   = (N + 3) / 4;      // one node per wave, 4 waves/block
    size_t N4 = (size_t)N * 4;

    // ---- layer 0: 16 -> 128 (compact bf16 hop chain H0..H3) ----
    k_prop16b<<<gpw, 256, 0, stream>>>(H0, H1, row_ptr, csr, N);
    k_prop16b<<<gpw, 256, 0, stream>>>(H1, H2, row_ptr, csr, N);
    k_prop16b<<<gpw, 256, 0, stream>>>(H2, H3, row_ptr, csr, N);
    k_mfma_gemm<true, false><<<gmfma, 256, 0, stream>>>(H0, 16, H1, 16, H2, 16, H3, 16,
                                                        64, Wt0, b0, Qa, nullptr, nullptr, N);

    // ---- layer 1: 128 -> 128 ----
    k_prop128b<<<gpw, 256, 0, stream>>>(Qa, 128,      S + 0,   384, row_ptr, csr, N);
    k_prop128b<<<gpw, 256, 0, stream>>>(S + 0, 384,   S + 128, 384, row_ptr, csr, N);
    k_prop128b<<<gpw, 256, 0, stream>>>(S + 128, 384, S + 256, 384, row_ptr, csr, N);
    k_mfma_gemm<false, false><<<gmfma, 256, 0, stream>>>(Qa, 128, S + 0, 384, S + 128, 384, S + 256, 384,
                                                         512, Wt1, b1, Qb, nullptr, nullptr, N);

    // ---- layer 2: 128 -> 128, Z fused into epilogue ----
    k_prop128b<<<gpw, 256, 0, stream>>>(Qb, 128,      S + 0,   384, row_ptr, csr, N);
    k_prop128b<<<gpw, 256, 0, stream>>>(S + 0, 384,   S + 128, 384, row_ptr, csr, N);
    k_prop128b<<<gpw, 256, 0, stream>>>(S + 128, 384, S + 256, 384, row_ptr, csr, N);
    k_mfma_gemm<false, true><<<gmfma, 256, 0, stream>>>(Qb, 128, S + 0, 384, S + 128, 384, S + 256, 384,
                                                        512, Wt2, b2, nullptr, Wz, Z, N);

    // ---- layer 3: 128 -> 4 via projected Horner on Z planes ----
    {
        int g = (N + 15) / 16;
        k_prop4_add<<<g, 256, 0, stream>>>(Z + 3 * N4, Z + 2 * N4, nullptr, T1, row_ptr, csr, N);
        k_prop4_add<<<g, 256, 0, stream>>>(T1,         Z + 1 * N4, nullptr, T2, row_ptr, csr, N);
        k_prop4_add<<<g, 256, 0, stream>>>(T2,         Z + 0 * N4, b3,      out, row_ptr, csr, N);
    }
}